// Round 3
// baseline (343.529 us; speedup 1.0000x reference)
//
#include <hip/hip_runtime.h>
#include <stdint.h>

// Problem constants
#define B_    32
#define L_    512
#define DIN_  768
#define H_    16
#define DH_   48
#define DOUT_ 768
#define NHEADS (B_ * H_)          // 512
#define HEADELEMS (L_ * DH_)      // 24576 elems per head
#define MROWS (B_ * L_)           // 16384

typedef short bf16x8 __attribute__((ext_vector_type(8)));  // 8 bf16 (4 VGPRs)
typedef float f32x4  __attribute__((ext_vector_type(4)));  // MFMA accumulator

// ---------------------------------------------------------------------------
// bf16 helpers (manual RNE)
// ---------------------------------------------------------------------------
__device__ __forceinline__ uint16_t f2bf(float f) {
  uint32_t u = __float_as_uint(f);
  u += 0x7fffu + ((u >> 16) & 1u);
  return (uint16_t)(u >> 16);
}
__device__ __forceinline__ uint32_t pack2bf(float lo, float hi) {
  uint32_t a = __float_as_uint(lo);
  a += 0x7fffu + ((a >> 16) & 1u);
  uint32_t b = __float_as_uint(hi);
  b += 0x7fffu + ((b >> 16) & 1u);
  return (a >> 16) | (b & 0xffff0000u);
}
// async global->LDS, 16B per lane
__device__ __forceinline__ void gload_lds16(const void* g, void* l) {
  __builtin_amdgcn_global_load_lds(
      (const __attribute__((address_space(1))) uint32_t*)g,
      (__attribute__((address_space(3))) uint32_t*)l, 16, 0, 0);
}
// bf16x8 fragment from LDS at 8B-aligned address
__device__ __forceinline__ bf16x8 lds_frag8(const uint16_t* p) {
  union { uint2 u[2]; bf16x8 v; } x;
  x.u[0] = *(const uint2*)(p);
  x.u[1] = *(const uint2*)(p + 4);
  return x.v;
}

// ---------------------------------------------------------------------------
// Kernel 0: canonicalize Q_len / V_len (int64-vs-int32 autodetect).
// ---------------------------------------------------------------------------
__global__ void lens_kernel(const int* __restrict__ qlen_raw,
                            const int* __restrict__ vlen_raw,
                            int* __restrict__ lens) {
  __shared__ int is64[2];
  int t = threadIdx.x;
  if (t < 2) {
    const int* src = (t == 0) ? qlen_raw : vlen_raw;
    int o = 0;
    for (int i = 0; i < 16; ++i) o |= src[2 * i + 1];
    is64[t] = (o == 0) ? 1 : 0;
  }
  __syncthreads();
  int which = t >> 5;
  int i = t & 31;
  const int* src = which ? vlen_raw : qlen_raw;
  lens[t] = is64[which] ? src[2 * i] : src[i];
}

// ---------------------------------------------------------------------------
// Kernel 1: W transpose+convert.  Wt[z][n][k] = bf16(W_z[k][n]).
// WQ pre-scaled by 1/sqrt(DH) (softmax scale folded out of attn hot loop).
// ---------------------------------------------------------------------------
__global__ void wconv_kernel(const float* __restrict__ WQ,
                             const float* __restrict__ WK,
                             const float* __restrict__ WV,
                             uint16_t* __restrict__ Wt) {
  const int z = blockIdx.z;
  const float* W = (z == 0) ? WQ : (z == 1) ? WK : WV;
  const float sc = (z == 0) ? 0.14433756729740643f : 1.0f;  // 1/sqrt(48)
  uint16_t* dst = Wt + (size_t)z * DIN_ * DOUT_;
  const int n  = blockIdx.x * 256 + threadIdx.x;
  const int k4 = blockIdx.y * 4;
  float f0 = W[(size_t)(k4 + 0) * DOUT_ + n] * sc;
  float f1 = W[(size_t)(k4 + 1) * DOUT_ + n] * sc;
  float f2 = W[(size_t)(k4 + 2) * DOUT_ + n] * sc;
  float f3 = W[(size_t)(k4 + 3) * DOUT_ + n] * sc;
  uint2 p;
  p.x = pack2bf(f0, f1);
  p.y = pack2bf(f2, f3);
  *(uint2*)&dst[(size_t)n * DIN_ + k4] = p;
}

// ---------------------------------------------------------------------------
// Kernel 1b (R2): X fp32 -> bf16 row-major, one streaming pass.
// Moves the fp32->bf16 conversion OFF mfma_proj's barrier-critical path
// (was 2 float4 loads + 8 pack VALU + ds_write per thread per K-step).
// ---------------------------------------------------------------------------
__global__ void xconv_kernel(const float* __restrict__ Xq,
                             const float* __restrict__ Xk,
                             const float* __restrict__ Xv,
                             uint16_t* __restrict__ Xbf) {
  const int z = blockIdx.y;
  const float* src = (z == 0) ? Xq : (z == 1) ? Xk : Xv;
  uint16_t* dst = Xbf + (size_t)z * MROWS * DIN_;
  const size_t i = ((size_t)blockIdx.x * 256 + threadIdx.x) * 8;
  float4 x0 = *(const float4*)(src + i);
  float4 x1 = *(const float4*)(src + i + 4);
  uint4 p;
  p.x = pack2bf(x0.x, x0.y); p.y = pack2bf(x0.z, x0.w);
  p.z = pack2bf(x1.x, x1.y); p.w = pack2bf(x1.z, x1.w);
  *(uint4*)(dst + i) = p;
}

// ---------------------------------------------------------------------------
// Kernel 2: MFMA projection GEMM v5 — pure m97 structure.
// 128m x 256n tile, BK=32, 512 threads (8 waves 2m x 4n), wave tile 64x64.
// BOTH operands staged via global_load_lds width-16 (zero staging VALU,
// zero ds_write).  LDS dest linear (HW requirement), source column
// pre-swizzled per rule #21; fragment reads XOR the chunk index ->
// conflict-free (verified 0 conflicts in R2).
// Per K-step per wave: 16 MFMA, 8 ds_read_b128, 3 gload_lds16/thread.
// ---------------------------------------------------------------------------
__global__ __launch_bounds__(512, 4) void mfma_proj(
    const uint16_t* __restrict__ Xbf, const uint16_t* __restrict__ Wt,
    uint16_t* __restrict__ qh, uint16_t* __restrict__ kh,
    uint16_t* __restrict__ vh) {
  const int z = blockIdx.z;
  const uint16_t* X = Xbf + (size_t)z * MROWS * DIN_;   // [m][k] bf16
  uint16_t* dst  = (z == 0) ? qh : (z == 1) ? kh : vh;
  const uint16_t* W = Wt + (size_t)z * DIN_ * DOUT_;    // [n][k] bf16

  __shared__ uint16_t As[128][32];   //  8 KB, chunk-swizzled
  __shared__ uint16_t Bs[256][32];   // 16 KB, chunk-swizzled

  const int t  = threadIdx.x;
  const int m0 = blockIdx.x * 128;
  const int n0 = blockIdx.y * 256;

  // staging slot s -> LDS row s>>2, physical chunk s&3 which holds
  // logical chunk (s&3)^((s>>3)&3).  (t and t+512 share the same swizzle
  // since 512 = 0 mod 32.)
  const int csw = ((t & 3) ^ ((t >> 3) & 3)) * 8;
  const uint16_t* aptr  = X + (size_t)(m0 + (t >> 2)) * DIN_ + csw;
  const uint16_t* bptr0 = W + (size_t)(n0 + (t >> 2)) * DIN_ + csw;
  const uint16_t* bptr1 = W + (size_t)(n0 + 128 + (t >> 2)) * DIN_ + csw;
  void* ldsA  = (char*)(&As[0][0]) + t * 16;
  void* ldsB0 = (char*)(&Bs[0][0]) + t * 16;
  void* ldsB1 = (char*)(&Bs[0][0]) + (t + 512) * 16;

  const int w = t >> 6, lane = t & 63;
  const int wm = (w & 1) * 64, wn = (w >> 1) * 64;
  const int fr = lane & 15;
  const int quad = lane >> 4;

  f32x4 acc[4][4];
#pragma unroll
  for (int i = 0; i < 4; ++i)
#pragma unroll
    for (int j = 0; j < 4; ++j) acc[i][j] = f32x4{0.f, 0.f, 0.f, 0.f};

  for (int kt = 0; kt < DIN_ / 32; ++kt) {
    const int k0 = kt * 32;
    gload_lds16(aptr + k0, ldsA);
    gload_lds16(bptr0 + k0, ldsB0);
    gload_lds16(bptr1 + k0, ldsB1);
    __syncthreads();   // drains vmcnt (compiler-inserted)

    bf16x8 af[4], bfr[4];
#pragma unroll
    for (int i = 0; i < 4; ++i) {
      const int r = wm + i * 16 + fr;
      af[i]  = *(const bf16x8*)&As[r][(quad ^ ((r >> 1) & 3)) * 8];
    }
#pragma unroll
    for (int j = 0; j < 4; ++j) {
      const int r = wn + j * 16 + fr;
      bfr[j] = *(const bf16x8*)&Bs[r][(quad ^ ((r >> 1) & 3)) * 8];
    }
#pragma unroll
    for (int mt = 0; mt < 4; ++mt)
#pragma unroll
      for (int nt = 0; nt < 4; ++nt)
        acc[mt][nt] = __builtin_amdgcn_mfma_f32_16x16x32_bf16(
            af[mt], bfr[nt], acc[mt][nt], 0, 0, 0);
    __syncthreads();
  }

  // epilogue: D[row=quad*4+r][col=fr] -> head-major bf16
#pragma unroll
  for (int mt = 0; mt < 4; ++mt) {
#pragma unroll
    for (int r = 0; r < 4; ++r) {
      const int m  = m0 + wm + mt * 16 + quad * 4 + r;
      const int bb = m >> 9;
      const int l  = m & 511;
#pragma unroll
      for (int nt = 0; nt < 4; ++nt) {
        const int n = n0 + wn + nt * 16 + fr;
        const int h = n / DH_;
        const int d = n - h * DH_;
        dst[(((size_t)bb * H_ + h) * L_ + l) * DH_ + d] = f2bf(acc[mt][nt][r]);
      }
    }
  }
}

// ---------------------------------------------------------------------------
// Kernel 3: MFMA attention v5 — max-free softmax, spill-free, single S pass.
//   p_unnorm = exp(s) (masked -> 0); L = row sum via shfl + LDS;
//   normalization folded into V: V'[q] = V[q]/L_q;  O += P_unnorm^T V'.
//   vlen==0 degenerate: e = (k<=q) -> exactly np's uniform-row result.
//   LDS rows padded to 36 (72B stride) -> fragment reads conflict-free.
// ---------------------------------------------------------------------------
__global__ __launch_bounds__(256, 2) void attn_mfma(
    const uint16_t* __restrict__ qh, const uint16_t* __restrict__ kh,
    const uint16_t* __restrict__ vh, const int* __restrict__ lens,
    float* __restrict__ out) {
  const int bh = blockIdx.x;
  const int b  = bh >> 4;
  const int h  = bh & 15;
  const int t    = threadIdx.x;
  const int w    = t >> 6;
  const int lane = t & 63;
  const int l15  = lane & 15;
  const int quad = lane >> 4;

  const int qlen = lens[b];
  const int vlen = lens[32 + b];
  const bool deg = (vlen == 0);
  const size_t head = (size_t)bh * HEADELEMS;

  __shared__ uint16_t Pt[4][128][36];  // 36864 B  [wave][k_loc][q_loc] (unnorm e)
  __shared__ uint16_t Vt[48][36];      //  3456 B  [d][q_loc] raw -> scaled
  __shared__ float    prt[4][32];      //   512 B  per-wave row sums

  const uint16_t* qbase = qh + head;
  const uint16_t* kbase = kh + head;
  const uint16_t* vbase = vh + head;

  f32x4 Oacc[8][3];
#pragma unroll
  for (int i = 0; i < 8; ++i)
#pragma unroll
    for (int dt = 0; dt < 3; ++dt) Oacc[i][dt] = f32x4{0.f, 0.f, 0.f, 0.f};

  for (int g = 0; g < 16; ++g) {
    const int q0 = g * 32;
    const int lim = q0 + 31 - 16 * w;   // tile i active iff 64*i <= lim

    __syncthreads();   // B0: prev-iter PV done reading Pt/Vt

    // ---- stage Vt[d][q_loc] raw bf16: 192 threads x 16B ----
    if (t < 192) {
      const int vq = t & 31, oct = t >> 5;      // oct = 0..5, 8 d's each
      uint4 u = *(const uint4*)(vbase + (size_t)(q0 + vq) * DH_ + oct * 8);
      const int d0 = oct * 8;
      Vt[d0 + 0][vq] = (uint16_t)(u.x);
      Vt[d0 + 1][vq] = (uint16_t)(u.x >> 16);
      Vt[d0 + 2][vq] = (uint16_t)(u.y);
      Vt[d0 + 3][vq] = (uint16_t)(u.y >> 16);
      Vt[d0 + 4][vq] = (uint16_t)(u.z);
      Vt[d0 + 5][vq] = (uint16_t)(u.z >> 16);
      Vt[d0 + 6][vq] = (uint16_t)(u.w);
      Vt[d0 + 7][vq] = (uint16_t)(u.w >> 16);
    }

    // ---- Q A-fragments (2 m-tiles x 2 K-steps), d 48..63 zero-padded ----
    bf16x8 aq[2][2];
#pragma unroll
    for (int mt = 0; mt < 2; ++mt) {
      const uint16_t* qp = qbase + (size_t)(q0 + mt * 16 + l15) * DH_;
      aq[mt][0] = *(const bf16x8*)(qp + quad * 8);
      bf16x8 zz = {0, 0, 0, 0, 0, 0, 0, 0};
      aq[mt][1] = zz;
      if (quad < 2) aq[mt][1] = *(const bf16x8*)(qp + 32 + quad * 8);
    }

    // ---- single pass: S-MFMA -> e=exp(s) -> row-sum + pack to Pt ----
    float lrun[2][4];
#pragma unroll
    for (int mt = 0; mt < 2; ++mt)
#pragma unroll
      for (int r = 0; r < 4; ++r) lrun[mt][r] = 0.0f;

#pragma unroll
    for (int i = 0; i < 8; ++i) {
      if (64 * i > lim) continue;   // wave-uniform causal tile skip
      const int kb = 64 * i + 16 * w;
      f32x4 s0 = {0.f, 0.f, 0.f, 0.f};
      f32x4 s1 = {0.f, 0.f, 0.f, 0.f};
      if (!deg) {
        const uint16_t* kp = kbase + (size_t)(kb + l15) * DH_;
        bf16x8 bk0 = *(const bf16x8*)(kp + quad * 8);
        bf16x8 bk1 = {0, 0, 0, 0, 0, 0, 0, 0};
        if (quad < 2) bk1 = *(const bf16x8*)(kp + 32 + quad * 8);
        s0 = __builtin_amdgcn_mfma_f32_16x16x32_bf16(aq[0][0], bk0, s0, 0, 0, 0);
        s0 = __builtin_amdgcn_mfma_f32_16x16x32_bf16(aq[0][1], bk1, s0, 0, 0, 0);
        s1 = __builtin_amdgcn_mfma_f32_16x16x32_bf16(aq[1][0], bk0, s1, 0, 0, 0);
        s1 = __builtin_amdgcn_mfma_f32_16x16x32_bf16(aq[1][1], bk1, s1, 0, 0, 0);
      }
      const int kc  = kb + l15;
      const int row = i * 16 + l15;
#pragma unroll
      for (int mt = 0; mt < 2; ++mt) {
        f32x4 sv = (mt == 0) ? s0 : s1;
        float p4[4];
#pragma unroll
        for (int r = 0; r < 4; ++r) {
          const int qrow = q0 + mt * 16 + quad * 4 + r;
          float e;
          if (deg) {
            e = (kc <= qrow) ? 1.0f : 0.0f;
          } else {
            // scale already folded into qh via WQ
            e = (kc < vlen && kc <= qrow) ? __expf(sv[r]) : 0.0f;
          }
          lrun[mt][r] += e;
          p4[r] = e;
        }
        const int col = mt * 16 + quad * 4;
        *(uint32_t*)&Pt[w][row][col]     = pack2bf(p4[0], p4[1]);
        *(uint32_t*)&Pt[w][row][col + 2] = pack2bf(p4[2], p4[3]);
      }
    }

    // ---- 16-lane sum reduce; write per-wave partials ----
#pragma unroll
    for (int mt = 0; mt < 2; ++mt)
#pragma unroll
      for (int r = 0; r < 4; ++r) {
        float l = lrun[mt][r];
#pragma unroll
        for (int off = 1; off < 16; off <<= 1) l += __shfl_xor(l, off, 64);
        lrun[mt][r] = l;
      }
    if (l15 == 0) {
#pragma unroll
      for (int mt = 0; mt < 2; ++mt)
#pragma unroll
        for (int r = 0; r < 4; ++r)
          prt[w][mt * 16 + quad * 4 + r] = lrun[mt][r];
    }
    __syncthreads();   // B1: prt + Pt + Vt-raw visible

    // ---- scale Vt rows by 1/L_q in place (q = t&31 is j-invariant) ----
    {
      const int q = t & 31;
      const float inv = __builtin_amdgcn_rcpf(
          prt[0][q] + prt[1][q] + prt[2][q] + prt[3][q]);
#pragma unroll
      for (int j = 0; j < 6; ++j) {
        const int d = (t >> 5) + 8 * j;
        float f = __uint_as_float((uint32_t)Vt[d][q] << 16) * inv;
        Vt[d][q] = f2bf(f);
      }
    }
    __syncthreads();   // B2: scaled Vt visible

    // ---- PV MFMAs: Oacc[k_loc][d] += P^T[k][q] V'[q][d] ----
    bf16x8 bv[3];
#pragma unroll
    for (int dt = 0; dt < 3; ++dt)
      bv[dt] = lds_frag8(&Vt[dt * 16 + l15][quad * 8]);
#pragma unroll
    for (int i = 0; i < 8; ++i) {
      if (64 * i > lim) continue;
      bf16x8 ap = lds_frag8(&Pt[w][i * 16 + l15][quad * 8]);
#pragma unroll
      for (int dt = 0; dt < 3; ++dt)
        Oacc[i][dt] = __builtin_amdgcn_mfma_f32_16x16x32_bf16(
            ap, bv[dt], Oacc[i][dt], 0, 0, 0);
    }
  }

  // ---- epilogue: Q_len row mask, fp32 out [B][L][H*DH] ----
#pragma unroll
  for (int i = 0; i < 8; ++i) {
#pragma unroll
    for (int r = 0; r < 4; ++r) {
      const int k_abs = 64 * i + 16 * w + quad * 4 + r;
      const float msk = (k_abs < qlen) ? 1.0f : 0.0f;
      float* orow = out + (size_t)(b * L_ + k_abs) * DOUT_ + h * DH_;
#pragma unroll
      for (int dt = 0; dt < 3; ++dt)
        orow[dt * 16 + l15] = Oacc[i][dt][r] * msk;
    }
  }
}

// ---------------------------------------------------------------------------
// launch
// ---------------------------------------------------------------------------
extern "C" void kernel_launch(void* const* d_in, const int* in_sizes, int n_in,
                              void* d_out, int out_size, void* d_ws, size_t ws_size,
                              hipStream_t stream) {
  const float* Qs  = (const float*)d_in[0];
  const float* Kse = (const float*)d_in[1];
  const float* Vs  = (const float*)d_in[2];
  const float* WQ  = (const float*)d_in[3];
  const float* WK  = (const float*)d_in[4];
  const float* WV  = (const float*)d_in[5];
  const int*   Qlen = (const int*)d_in[6];
  const int*   Vlen = (const int*)d_in[7];
  float* out = (float*)d_out;

  char* ws = (char*)d_ws;
  int* lens = (int*)ws;
  uint16_t* qh  = (uint16_t*)(ws + 256);
  uint16_t* kh  = qh + (size_t)B_ * H_ * L_ * DH_;
  uint16_t* vh  = kh + (size_t)B_ * H_ * L_ * DH_;
  uint16_t* Wt  = vh + (size_t)B_ * H_ * L_ * DH_;
  uint16_t* Xbf = Wt + (size_t)3 * DIN_ * DOUT_;   // 3 x 16384 x 768 bf16

  lens_kernel<<<1, 64, 0, stream>>>(Qlen, Vlen, lens);
  wconv_kernel<<<dim3(3, 192, 3), 256, 0, stream>>>(WQ, WK, WV, Wt);
  xconv_kernel<<<dim3(MROWS * DIN_ / 2048, 3), 256, 0, stream>>>(Qs, Kse, Vs, Xbf);
  mfma_proj<<<dim3(MROWS / 128, DOUT_ / 256, 3), 512, 0, stream>>>(
      Xbf, Wt, qh, kh, vh);
  attn_mfma<<<NHEADS, 256, 0, stream>>>(qh, kh, vh, lens, out);
}

// Round 4
// 339.840 us; speedup vs baseline: 1.0109x; 1.0109x over previous
//
#include <hip/hip_runtime.h>
#include <stdint.h>

// Problem constants
#define B_    32
#define L_    512
#define DIN_  768
#define H_    16
#define DH_   48
#define DOUT_ 768
#define NHEADS (B_ * H_)          // 512
#define HEADELEMS (L_ * DH_)      // 24576 elems per head
#define MROWS (B_ * L_)           // 16384

typedef short bf16x8 __attribute__((ext_vector_type(8)));  // 8 bf16 (4 VGPRs)
typedef float f32x4  __attribute__((ext_vector_type(4)));  // MFMA accumulator

// ---------------------------------------------------------------------------
// bf16 helpers (manual RNE)
// ---------------------------------------------------------------------------
__device__ __forceinline__ uint16_t f2bf(float f) {
  uint32_t u = __float_as_uint(f);
  u += 0x7fffu + ((u >> 16) & 1u);
  return (uint16_t)(u >> 16);
}
__device__ __forceinline__ uint32_t pack2bf(float lo, float hi) {
  uint32_t a = __float_as_uint(lo);
  a += 0x7fffu + ((a >> 16) & 1u);
  uint32_t b = __float_as_uint(hi);
  b += 0x7fffu + ((b >> 16) & 1u);
  return (a >> 16) | (b & 0xffff0000u);
}
// async global->LDS, 16B per lane
__device__ __forceinline__ void gload_lds16(const void* g, void* l) {
  __builtin_amdgcn_global_load_lds(
      (const __attribute__((address_space(1))) uint32_t*)g,
      (__attribute__((address_space(3))) uint32_t*)l, 16, 0, 0);
}
// bf16x8 fragment from LDS at 8B-aligned address
__device__ __forceinline__ bf16x8 lds_frag8(const uint16_t* p) {
  union { uint2 u[2]; bf16x8 v; } x;
  x.u[0] = *(const uint2*)(p);
  x.u[1] = *(const uint2*)(p + 4);
  return x.v;
}

// ---------------------------------------------------------------------------
// Kernel 0: canonicalize Q_len / V_len (int64-vs-int32 autodetect).
// ---------------------------------------------------------------------------
__global__ void lens_kernel(const int* __restrict__ qlen_raw,
                            const int* __restrict__ vlen_raw,
                            int* __restrict__ lens) {
  __shared__ int is64[2];
  int t = threadIdx.x;
  if (t < 2) {
    const int* src = (t == 0) ? qlen_raw : vlen_raw;
    int o = 0;
    for (int i = 0; i < 16; ++i) o |= src[2 * i + 1];
    is64[t] = (o == 0) ? 1 : 0;
  }
  __syncthreads();
  int which = t >> 5;
  int i = t & 31;
  const int* src = which ? vlen_raw : qlen_raw;
  lens[t] = is64[which] ? src[2 * i] : src[i];
}

// ---------------------------------------------------------------------------
// Kernel 1: W transpose+convert.  Wt[z][n][k] = bf16(W_z[k][n]).
// WQ pre-scaled by 1/sqrt(DH) (softmax scale folded out of attn hot loop).
// ---------------------------------------------------------------------------
__global__ void wconv_kernel(const float* __restrict__ WQ,
                             const float* __restrict__ WK,
                             const float* __restrict__ WV,
                             uint16_t* __restrict__ Wt) {
  const int z = blockIdx.z;
  const float* W = (z == 0) ? WQ : (z == 1) ? WK : WV;
  const float sc = (z == 0) ? 0.14433756729740643f : 1.0f;  // 1/sqrt(48)
  uint16_t* dst = Wt + (size_t)z * DIN_ * DOUT_;
  const int n  = blockIdx.x * 256 + threadIdx.x;
  const int k4 = blockIdx.y * 4;
  float f0 = W[(size_t)(k4 + 0) * DOUT_ + n] * sc;
  float f1 = W[(size_t)(k4 + 1) * DOUT_ + n] * sc;
  float f2 = W[(size_t)(k4 + 2) * DOUT_ + n] * sc;
  float f3 = W[(size_t)(k4 + 3) * DOUT_ + n] * sc;
  uint2 p;
  p.x = pack2bf(f0, f1);
  p.y = pack2bf(f2, f3);
  *(uint2*)&dst[(size_t)n * DIN_ + k4] = p;
}

// ---------------------------------------------------------------------------
// Kernel 2: MFMA projection GEMM v6 — fused fp32-A + 2-phase double-buffer.
// 128m x 256n tile, BK=32, 512 threads (8 waves 2m x 4n), wave tile 64x64.
// R3 post-mortem: 1-phase schedule exposed full load latency each K-step
// (gload -> immediate barrier drain), and the separate xconv pass cost
// ~48 us of pure streaming.  v6:
//  - A staged as RAW fp32 via global_load_lds (no xconv pass, no staging
//    VALU); converted to bf16 on the READ side with v_cvt_pk_bf16_f32
//    (16 insts/wave/K-step, hidden under 16 MFMA).
//  - 2-phase dbuf (catalog T3-minimum): STAGE(kt+1) issued BEFORE compute
//    of kt, single __syncthreads per K-step -> HBM latency hides under
//    ds_read+cvt+MFMA.  LDS 2x(16+16)=64 KB -> 2 blocks/CU.
// Swizzles (rule #21, both-sides):
//  - A fp32 rows are 128B (=32 banks): 8x16B chunks/row, phys = log ^ (row&7),
//    source pre-swizzled, reader XORs -> 2-way max (free).
//  - B bf16 rows are 64B: 4x16B chunks, phys = log ^ ((row>>1)&3)
//    (unchanged from R2/R3, measured 0 conflicts).
// ---------------------------------------------------------------------------
__global__ __launch_bounds__(512, 4) void mfma_proj(
    const float* __restrict__ Xq, const float* __restrict__ Xk,
    const float* __restrict__ Xv, const uint16_t* __restrict__ Wt,
    uint16_t* __restrict__ qh, uint16_t* __restrict__ kh,
    uint16_t* __restrict__ vh) {
  const int z = blockIdx.z;
  const float* X = (z == 0) ? Xq : (z == 1) ? Xk : Xv;
  uint16_t* dst  = (z == 0) ? qh : (z == 1) ? kh : vh;
  const uint16_t* W = Wt + (size_t)z * DIN_ * DOUT_;    // [n][k] bf16

  __shared__ float    Asf[2][128][32];   // 2 x 16 KB fp32, chunk-swizzled
  __shared__ uint16_t Bs[2][256][32];    // 2 x 16 KB bf16, chunk-swizzled

  const int t  = threadIdx.x;
  const int m0 = blockIdx.x * 128;
  const int n0 = blockIdx.y * 256;

  // A staging: slot t covers LDS row t>>3 (rows 0..63), phys chunk t&7;
  // slot t+512 covers row (t>>3)+64, same phys chunk.  Logical chunk
  // l = phys ^ (row&7); row+64 keeps the same l (64 % 8 == 0).
  const int arow = t >> 3;
  const int achk = (t & 7) ^ (arow & 7);
  const float* aptr0 = X + (size_t)(m0 + arow) * DIN_ + achk * 4;
  const float* aptr1 = aptr0 + (size_t)64 * DIN_;

  // B staging: slot t -> row t>>2, phys chunk t&3, logical ^((row>>1)&3)
  const int bcsw = ((t & 3) ^ ((t >> 3) & 3)) * 8;
  const uint16_t* bptr0 = W + (size_t)(n0 + (t >> 2)) * DIN_ + bcsw;
  const uint16_t* bptr1 = W + (size_t)(n0 + 128 + (t >> 2)) * DIN_ + bcsw;

  char* aB = (char*)&Asf[0][0][0] + t * 16;   // buffer stride 16384 B
  char* bB = (char*)&Bs[0][0][0] + t * 16;    // buffer stride 16384 B

#define STAGE_(buf_, kt_)                                   \
  {                                                         \
    const int k0_ = (kt_) * 32;                             \
    gload_lds16(aptr0 + k0_, aB + (buf_) * 16384);          \
    gload_lds16(aptr1 + k0_, aB + (buf_) * 16384 + 8192);   \
    gload_lds16(bptr0 + k0_, bB + (buf_) * 16384);          \
    gload_lds16(bptr1 + k0_, bB + (buf_) * 16384 + 8192);   \
  }

  const int w = t >> 6, lane = t & 63;
  const int wm = (w & 1) * 64, wn = (w >> 1) * 64;
  const int fr = lane & 15;
  const int quad = lane >> 4;
  // A fragment: rows wm+mt*16+fr; (r&7)==(fr&7) since wm,16*mt = 0 mod 8.
  const int rx  = fr & 7;
  const int ac0 = ((2 * quad)     ^ rx) * 4;   // float idx of 1st 16B chunk
  const int ac1 = ((2 * quad + 1) ^ rx) * 4;   // float idx of 2nd 16B chunk

  f32x4 acc[4][4];
#pragma unroll
  for (int i = 0; i < 4; ++i)
#pragma unroll
    for (int j = 0; j < 4; ++j) acc[i][j] = f32x4{0.f, 0.f, 0.f, 0.f};

  STAGE_(0, 0);
  __syncthreads();
  int cur = 0;
  for (int kt = 0; kt < DIN_ / 32; ++kt) {
    if (kt + 1 < DIN_ / 32) STAGE_(cur ^ 1, kt + 1);   // prefetch next tile

    bf16x8 bfr[4];
#pragma unroll
    for (int j = 0; j < 4; ++j) {
      const int r = wn + j * 16 + fr;
      bfr[j] = *(const bf16x8*)&Bs[cur][r][(quad ^ ((r >> 1) & 3)) * 8];
    }
#pragma unroll
    for (int mt = 0; mt < 4; ++mt) {
      const float* ar = &Asf[cur][wm + mt * 16 + fr][0];
      float4 a0 = *(const float4*)(ar + ac0);
      float4 a1 = *(const float4*)(ar + ac1);
      union { uint32_t u[4]; bf16x8 v; } cv;
      asm("v_cvt_pk_bf16_f32 %0, %1, %2" : "=v"(cv.u[0]) : "v"(a0.x), "v"(a0.y));
      asm("v_cvt_pk_bf16_f32 %0, %1, %2" : "=v"(cv.u[1]) : "v"(a0.z), "v"(a0.w));
      asm("v_cvt_pk_bf16_f32 %0, %1, %2" : "=v"(cv.u[2]) : "v"(a1.x), "v"(a1.y));
      asm("v_cvt_pk_bf16_f32 %0, %1, %2" : "=v"(cv.u[3]) : "v"(a1.z), "v"(a1.w));
#pragma unroll
      for (int nt = 0; nt < 4; ++nt)
        acc[mt][nt] = __builtin_amdgcn_mfma_f32_16x16x32_bf16(
            cv.v, bfr[nt], acc[mt][nt], 0, 0, 0);
    }
    __syncthreads();   // drains this wave's prefetch vmcnt; releases cur buf
    cur ^= 1;
  }
#undef STAGE_

  // epilogue: D[row=quad*4+r][col=fr] -> head-major bf16
#pragma unroll
  for (int mt = 0; mt < 4; ++mt) {
#pragma unroll
    for (int r = 0; r < 4; ++r) {
      const int m  = m0 + wm + mt * 16 + quad * 4 + r;
      const int bb = m >> 9;
      const int l  = m & 511;
#pragma unroll
      for (int nt = 0; nt < 4; ++nt) {
        const int n = n0 + wn + nt * 16 + fr;
        const int h = n / DH_;
        const int d = n - h * DH_;
        dst[(((size_t)bb * H_ + h) * L_ + l) * DH_ + d] = f2bf(acc[mt][nt][r]);
      }
    }
  }
}

// ---------------------------------------------------------------------------
// Kernel 3: MFMA attention v5 — max-free softmax, spill-free, single S pass.
//   p_unnorm = exp(s) (masked -> 0); L = row sum via shfl + LDS;
//   normalization folded into V: V'[q] = V[q]/L_q;  O += P_unnorm^T V'.
//   vlen==0 degenerate: e = (k<=q) -> exactly np's uniform-row result.
//   LDS rows padded to 36 (72B stride) -> fragment reads conflict-free.
// ---------------------------------------------------------------------------
__global__ __launch_bounds__(256, 2) void attn_mfma(
    const uint16_t* __restrict__ qh, const uint16_t* __restrict__ kh,
    const uint16_t* __restrict__ vh, const int* __restrict__ lens,
    float* __restrict__ out) {
  const int bh = blockIdx.x;
  const int b  = bh >> 4;
  const int h  = bh & 15;
  const int t    = threadIdx.x;
  const int w    = t >> 6;
  const int lane = t & 63;
  const int l15  = lane & 15;
  const int quad = lane >> 4;

  const int qlen = lens[b];
  const int vlen = lens[32 + b];
  const bool deg = (vlen == 0);
  const size_t head = (size_t)bh * HEADELEMS;

  __shared__ uint16_t Pt[4][128][36];  // 36864 B  [wave][k_loc][q_loc] (unnorm e)
  __shared__ uint16_t Vt[48][36];      //  3456 B  [d][q_loc] raw -> scaled
  __shared__ float    prt[4][32];      //   512 B  per-wave row sums

  const uint16_t* qbase = qh + head;
  const uint16_t* kbase = kh + head;
  const uint16_t* vbase = vh + head;

  f32x4 Oacc[8][3];
#pragma unroll
  for (int i = 0; i < 8; ++i)
#pragma unroll
    for (int dt = 0; dt < 3; ++dt) Oacc[i][dt] = f32x4{0.f, 0.f, 0.f, 0.f};

  for (int g = 0; g < 16; ++g) {
    const int q0 = g * 32;
    const int lim = q0 + 31 - 16 * w;   // tile i active iff 64*i <= lim

    __syncthreads();   // B0: prev-iter PV done reading Pt/Vt

    // ---- stage Vt[d][q_loc] raw bf16: 192 threads x 16B ----
    if (t < 192) {
      const int vq = t & 31, oct = t >> 5;      // oct = 0..5, 8 d's each
      uint4 u = *(const uint4*)(vbase + (size_t)(q0 + vq) * DH_ + oct * 8);
      const int d0 = oct * 8;
      Vt[d0 + 0][vq] = (uint16_t)(u.x);
      Vt[d0 + 1][vq] = (uint16_t)(u.x >> 16);
      Vt[d0 + 2][vq] = (uint16_t)(u.y);
      Vt[d0 + 3][vq] = (uint16_t)(u.y >> 16);
      Vt[d0 + 4][vq] = (uint16_t)(u.z);
      Vt[d0 + 5][vq] = (uint16_t)(u.z >> 16);
      Vt[d0 + 6][vq] = (uint16_t)(u.w);
      Vt[d0 + 7][vq] = (uint16_t)(u.w >> 16);
    }

    // ---- Q A-fragments (2 m-tiles x 2 K-steps), d 48..63 zero-padded ----
    bf16x8 aq[2][2];
#pragma unroll
    for (int mt = 0; mt < 2; ++mt) {
      const uint16_t* qp = qbase + (size_t)(q0 + mt * 16 + l15) * DH_;
      aq[mt][0] = *(const bf16x8*)(qp + quad * 8);
      bf16x8 zz = {0, 0, 0, 0, 0, 0, 0, 0};
      aq[mt][1] = zz;
      if (quad < 2) aq[mt][1] = *(const bf16x8*)(qp + 32 + quad * 8);
    }

    // ---- single pass: S-MFMA -> e=exp(s) -> row-sum + pack to Pt ----
    float lrun[2][4];
#pragma unroll
    for (int mt = 0; mt < 2; ++mt)
#pragma unroll
      for (int r = 0; r < 4; ++r) lrun[mt][r] = 0.0f;

#pragma unroll
    for (int i = 0; i < 8; ++i) {
      if (64 * i > lim) continue;   // wave-uniform causal tile skip
      const int kb = 64 * i + 16 * w;
      f32x4 s0 = {0.f, 0.f, 0.f, 0.f};
      f32x4 s1 = {0.f, 0.f, 0.f, 0.f};
      if (!deg) {
        const uint16_t* kp = kbase + (size_t)(kb + l15) * DH_;
        bf16x8 bk0 = *(const bf16x8*)(kp + quad * 8);
        bf16x8 bk1 = {0, 0, 0, 0, 0, 0, 0, 0};
        if (quad < 2) bk1 = *(const bf16x8*)(kp + 32 + quad * 8);
        s0 = __builtin_amdgcn_mfma_f32_16x16x32_bf16(aq[0][0], bk0, s0, 0, 0, 0);
        s0 = __builtin_amdgcn_mfma_f32_16x16x32_bf16(aq[0][1], bk1, s0, 0, 0, 0);
        s1 = __builtin_amdgcn_mfma_f32_16x16x32_bf16(aq[1][0], bk0, s1, 0, 0, 0);
        s1 = __builtin_amdgcn_mfma_f32_16x16x32_bf16(aq[1][1], bk1, s1, 0, 0, 0);
      }
      const int kc  = kb + l15;
      const int row = i * 16 + l15;
#pragma unroll
      for (int mt = 0; mt < 2; ++mt) {
        f32x4 sv = (mt == 0) ? s0 : s1;
        float p4[4];
#pragma unroll
        for (int r = 0; r < 4; ++r) {
          const int qrow = q0 + mt * 16 + quad * 4 + r;
          float e;
          if (deg) {
            e = (kc <= qrow) ? 1.0f : 0.0f;
          } else {
            // scale already folded into qh via WQ
            e = (kc < vlen && kc <= qrow) ? __expf(sv[r]) : 0.0f;
          }
          lrun[mt][r] += e;
          p4[r] = e;
        }
        const int col = mt * 16 + quad * 4;
        *(uint32_t*)&Pt[w][row][col]     = pack2bf(p4[0], p4[1]);
        *(uint32_t*)&Pt[w][row][col + 2] = pack2bf(p4[2], p4[3]);
      }
    }

    // ---- 16-lane sum reduce; write per-wave partials ----
#pragma unroll
    for (int mt = 0; mt < 2; ++mt)
#pragma unroll
      for (int r = 0; r < 4; ++r) {
        float l = lrun[mt][r];
#pragma unroll
        for (int off = 1; off < 16; off <<= 1) l += __shfl_xor(l, off, 64);
        lrun[mt][r] = l;
      }
    if (l15 == 0) {
#pragma unroll
      for (int mt = 0; mt < 2; ++mt)
#pragma unroll
        for (int r = 0; r < 4; ++r)
          prt[w][mt * 16 + quad * 4 + r] = lrun[mt][r];
    }
    __syncthreads();   // B1: prt + Pt + Vt-raw visible

    // ---- scale Vt rows by 1/L_q in place (q = t&31 is j-invariant) ----
    {
      const int q = t & 31;
      const float inv = __builtin_amdgcn_rcpf(
          prt[0][q] + prt[1][q] + prt[2][q] + prt[3][q]);
#pragma unroll
      for (int j = 0; j < 6; ++j) {
        const int d = (t >> 5) + 8 * j;
        float f = __uint_as_float((uint32_t)Vt[d][q] << 16) * inv;
        Vt[d][q] = f2bf(f);
      }
    }
    __syncthreads();   // B2: scaled Vt visible

    // ---- PV MFMAs: Oacc[k_loc][d] += P^T[k][q] V'[q][d] ----
    bf16x8 bv[3];
#pragma unroll
    for (int dt = 0; dt < 3; ++dt)
      bv[dt] = lds_frag8(&Vt[dt * 16 + l15][quad * 8]);
#pragma unroll
    for (int i = 0; i < 8; ++i) {
      if (64 * i > lim) continue;
      bf16x8 ap = lds_frag8(&Pt[w][i * 16 + l15][quad * 8]);
#pragma unroll
      for (int dt = 0; dt < 3; ++dt)
        Oacc[i][dt] = __builtin_amdgcn_mfma_f32_16x16x32_bf16(
            ap, bv[dt], Oacc[i][dt], 0, 0, 0);
    }
  }

  // ---- epilogue: Q_len row mask, fp32 out [B][L][H*DH] ----
#pragma unroll
  for (int i = 0; i < 8; ++i) {
#pragma unroll
    for (int r = 0; r < 4; ++r) {
      const int k_abs = 64 * i + 16 * w + quad * 4 + r;
      const float msk = (k_abs < qlen) ? 1.0f : 0.0f;
      float* orow = out + (size_t)(b * L_ + k_abs) * DOUT_ + h * DH_;
#pragma unroll
      for (int dt = 0; dt < 3; ++dt)
        orow[dt * 16 + l15] = Oacc[i][dt][r] * msk;
    }
  }
}

// ---------------------------------------------------------------------------
// launch
// ---------------------------------------------------------------------------
extern "C" void kernel_launch(void* const* d_in, const int* in_sizes, int n_in,
                              void* d_out, int out_size, void* d_ws, size_t ws_size,
                              hipStream_t stream) {
  const float* Qs  = (const float*)d_in[0];
  const float* Kse = (const float*)d_in[1];
  const float* Vs  = (const float*)d_in[2];
  const float* WQ  = (const float*)d_in[3];
  const float* WK  = (const float*)d_in[4];
  const float* WV  = (const float*)d_in[5];
  const int*   Qlen = (const int*)d_in[6];
  const int*   Vlen = (const int*)d_in[7];
  float* out = (float*)d_out;

  char* ws = (char*)d_ws;
  int* lens = (int*)ws;
  uint16_t* qh  = (uint16_t*)(ws + 256);
  uint16_t* kh  = qh + (size_t)B_ * H_ * L_ * DH_;
  uint16_t* vh  = kh + (size_t)B_ * H_ * L_ * DH_;
  uint16_t* Wt  = vh + (size_t)B_ * H_ * L_ * DH_;

  lens_kernel<<<1, 64, 0, stream>>>(Qlen, Vlen, lens);
  wconv_kernel<<<dim3(3, 192, 3), 256, 0, stream>>>(WQ, WK, WV, Wt);
  mfma_proj<<<dim3(MROWS / 128, DOUT_ / 256, 3), 512, 0, stream>>>(
      Qs, Kse, Vs, Wt, qh, kh, vh);
  attn_mfma<<<NHEADS, 256, 0, stream>>>(qh, kh, vh, lens, out);
}

// Round 5
// 331.732 us; speedup vs baseline: 1.0356x; 1.0244x over previous
//
#include <hip/hip_runtime.h>
#include <stdint.h>

// Problem constants
#define B_    32
#define L_    512
#define DIN_  768
#define H_    16
#define DH_   48
#define DOUT_ 768
#define NHEADS (B_ * H_)          // 512
#define HEADELEMS (L_ * DH_)      // 24576 elems per head
#define MROWS (B_ * L_)           // 16384

typedef short bf16x8 __attribute__((ext_vector_type(8)));  // 8 bf16 (4 VGPRs)
typedef float f32x4  __attribute__((ext_vector_type(4)));  // MFMA accumulator

// ---------------------------------------------------------------------------
// bf16 helpers (manual RNE)
// ---------------------------------------------------------------------------
__device__ __forceinline__ uint16_t f2bf(float f) {
  uint32_t u = __float_as_uint(f);
  u += 0x7fffu + ((u >> 16) & 1u);
  return (uint16_t)(u >> 16);
}
__device__ __forceinline__ uint32_t pack2bf(float lo, float hi) {
  uint32_t a = __float_as_uint(lo);
  a += 0x7fffu + ((a >> 16) & 1u);
  uint32_t b = __float_as_uint(hi);
  b += 0x7fffu + ((b >> 16) & 1u);
  return (a >> 16) | (b & 0xffff0000u);
}
// async global->LDS, 16B per lane
__device__ __forceinline__ void gload_lds16(const void* g, void* l) {
  __builtin_amdgcn_global_load_lds(
      (const __attribute__((address_space(1))) uint32_t*)g,
      (__attribute__((address_space(3))) uint32_t*)l, 16, 0, 0);
}
// bf16x8 fragment from LDS at 8B-aligned address
__device__ __forceinline__ bf16x8 lds_frag8(const uint16_t* p) {
  union { uint2 u[2]; bf16x8 v; } x;
  x.u[0] = *(const uint2*)(p);
  x.u[1] = *(const uint2*)(p + 4);
  return x.v;
}

// ---------------------------------------------------------------------------
// Kernel 0: canonicalize Q_len / V_len (int64-vs-int32 autodetect).
// ---------------------------------------------------------------------------
__global__ void lens_kernel(const int* __restrict__ qlen_raw,
                            const int* __restrict__ vlen_raw,
                            int* __restrict__ lens) {
  __shared__ int is64[2];
  int t = threadIdx.x;
  if (t < 2) {
    const int* src = (t == 0) ? qlen_raw : vlen_raw;
    int o = 0;
    for (int i = 0; i < 16; ++i) o |= src[2 * i + 1];
    is64[t] = (o == 0) ? 1 : 0;
  }
  __syncthreads();
  int which = t >> 5;
  int i = t & 31;
  const int* src = which ? vlen_raw : qlen_raw;
  lens[t] = is64[which] ? src[2 * i] : src[i];
}

// ---------------------------------------------------------------------------
// Kernel 1: W transpose+convert.  Wt[z][n][k] = bf16(W_z[k][n]).
// WQ pre-scaled by 1/sqrt(DH) (softmax scale folded out of attn hot loop).
// ---------------------------------------------------------------------------
__global__ void wconv_kernel(const float* __restrict__ WQ,
                             const float* __restrict__ WK,
                             const float* __restrict__ WV,
                             uint16_t* __restrict__ Wt) {
  const int z = blockIdx.z;
  const float* W = (z == 0) ? WQ : (z == 1) ? WK : WV;
  const float sc = (z == 0) ? 0.14433756729740643f : 1.0f;  // 1/sqrt(48)
  uint16_t* dst = Wt + (size_t)z * DIN_ * DOUT_;
  const int n  = blockIdx.x * 256 + threadIdx.x;
  const int k4 = blockIdx.y * 4;
  float f0 = W[(size_t)(k4 + 0) * DOUT_ + n] * sc;
  float f1 = W[(size_t)(k4 + 1) * DOUT_ + n] * sc;
  float f2 = W[(size_t)(k4 + 2) * DOUT_ + n] * sc;
  float f3 = W[(size_t)(k4 + 3) * DOUT_ + n] * sc;
  uint2 p;
  p.x = pack2bf(f0, f1);
  p.y = pack2bf(f2, f3);
  *(uint2*)&dst[(size_t)n * DIN_ + k4] = p;
}

// ---------------------------------------------------------------------------
// Kernel 2: MFMA projection GEMM v8 — bf16 LDS + reg-staged A + 2-phase dbuf.
// 128m x 256n tile, BK=32, 512 threads (8 waves 2m x 4n), wave tile 64x64.
// R4 post-mortem: fp32-A-in-LDS doubled A ds_read traffic, re-introduced
// bank conflicts (7.1e6: 128B rows are bank-degenerate), and put a cvt
// chain between ds_read and MFMA -> 134us.  v8 reverts LDS to the
// R3-proven bf16 [128][32]/[256][32] chunk-swizzled layout (measured 0
// conflicts, single ds_read_b128 per fragment) but keeps:
//  - no xconv pass: A staged fp32 global -> regs -> pack2bf ->
//    ds_write_b128 bf16 (T14 issue-early / write-late; pack VALU sits
//    after the MFMA block, off the fragment critical path);
//  - 2-phase double-buffer, one barrier per K-step: prefetch(kt+1) issued
//    BEFORE compute(kt), A-pack+write after MFMAs, barrier drains
//    B-gload vmcnt + A-write lgkm.  X fp32 re-read over 3 n-blocks is
//    L3-absorbed (R4 measured FETCH ~= unique bytes).
// LDS 2*(8+16) = 48 KB -> 2 blocks/CU at launch_bounds(512,4).
// ---------------------------------------------------------------------------
__global__ __launch_bounds__(512, 4) void mfma_proj(
    const float* __restrict__ Xq, const float* __restrict__ Xk,
    const float* __restrict__ Xv, const uint16_t* __restrict__ Wt,
    uint16_t* __restrict__ qh, uint16_t* __restrict__ kh,
    uint16_t* __restrict__ vh) {
  const int z = blockIdx.z;
  const float* X = (z == 0) ? Xq : (z == 1) ? Xk : Xv;
  uint16_t* dst  = (z == 0) ? qh : (z == 1) ? kh : vh;
  const uint16_t* W = Wt + (size_t)z * DIN_ * DOUT_;    // [n][k] bf16

  __shared__ uint16_t As[2][128][32];   // 2 x 8 KB bf16, chunk-swizzled
  __shared__ uint16_t Bs[2][256][32];   // 2 x 16 KB bf16, chunk-swizzled

  const int t  = threadIdx.x;
  const int m0 = blockIdx.x * 128;
  const int n0 = blockIdx.y * 256;

  // slot t -> LDS row t>>2; phys chunk t&3 holds logical chunk
  // csw = (t&3)^((row>>1)&3)  (rows are 64B: 4 x 16B chunks).
  const int csw = (t & 3) ^ ((t >> 3) & 3);

  // A: thread owns row t>>2, loads logical chunk csw as 8 fp32 (32B),
  // packs to bf16, writes 16B to phys slot t&3 of its row.
  const float* aptr = X + (size_t)(m0 + (t >> 2)) * DIN_ + csw * 8;
  char* aWb = (char*)&As[0][0][0] + (t >> 2) * 64 + (t & 3) * 16;

  // B: global_load_lds, linear LDS dest, source column pre-swizzled.
  const uint16_t* bptr0 = W + (size_t)(n0 + (t >> 2)) * DIN_ + csw * 8;
  const uint16_t* bptr1 = W + (size_t)(n0 + 128 + (t >> 2)) * DIN_ + csw * 8;
  char* bB = (char*)&Bs[0][0][0] + t * 16;

  const int w = t >> 6, lane = t & 63;
  const int wm = (w & 1) * 64, wn = (w >> 1) * 64;
  const int fr = lane & 15;
  const int quad = lane >> 4;

  f32x4 acc[4][4];
#pragma unroll
  for (int i = 0; i < 4; ++i)
#pragma unroll
    for (int j = 0; j < 4; ++j) acc[i][j] = f32x4{0.f, 0.f, 0.f, 0.f};

  // ---- prologue: stage K-tile 0 into buffer 0 ----
  {
    gload_lds16(bptr0, bB);
    gload_lds16(bptr1, bB + 8192);
    float4 x0 = *(const float4*)(aptr);
    float4 x1 = *(const float4*)(aptr + 4);
    uint4 pA;
    pA.x = pack2bf(x0.x, x0.y); pA.y = pack2bf(x0.z, x0.w);
    pA.z = pack2bf(x1.x, x1.y); pA.w = pack2bf(x1.z, x1.w);
    *(uint4*)aWb = pA;
    __syncthreads();
  }

  int cur = 0;
  for (int kt = 0; kt < DIN_ / 32; ++kt) {
    const int nxt = cur ^ 1;
    float4 x0{}, x1{};
    const bool pre = (kt + 1 < DIN_ / 32);
    if (pre) {  // issue next-tile loads BEFORE compute (latency hides)
      const int k0 = (kt + 1) * 32;
      gload_lds16(bptr0 + k0, bB + nxt * 16384);
      gload_lds16(bptr1 + k0, bB + nxt * 16384 + 8192);
      x0 = *(const float4*)(aptr + k0);
      x1 = *(const float4*)(aptr + k0 + 4);
    }

    // ---- compute on buffer cur ----
    bf16x8 af[4], bfr[4];
#pragma unroll
    for (int i = 0; i < 4; ++i) {
      const int r = wm + i * 16 + fr;
      af[i]  = *(const bf16x8*)&As[cur][r][(quad ^ ((r >> 1) & 3)) * 8];
    }
#pragma unroll
    for (int j = 0; j < 4; ++j) {
      const int r = wn + j * 16 + fr;
      bfr[j] = *(const bf16x8*)&Bs[cur][r][(quad ^ ((r >> 1) & 3)) * 8];
    }
#pragma unroll
    for (int mt = 0; mt < 4; ++mt)
#pragma unroll
      for (int nt = 0; nt < 4; ++nt)
        acc[mt][nt] = __builtin_amdgcn_mfma_f32_16x16x32_bf16(
            af[mt], bfr[nt], acc[mt][nt], 0, 0, 0);

    if (pre) {  // write-late: pack A(kt+1) after the MFMA block
      uint4 pA;
      pA.x = pack2bf(x0.x, x0.y); pA.y = pack2bf(x0.z, x0.w);
      pA.z = pack2bf(x1.x, x1.y); pA.w = pack2bf(x1.z, x1.w);
      *(uint4*)(aWb + nxt * 8192) = pA;
    }
    __syncthreads();   // drains B-gload vmcnt + A-write lgkm; releases cur
    cur = nxt;
  }

  // epilogue: D[row=quad*4+r][col=fr] -> head-major bf16
#pragma unroll
  for (int mt = 0; mt < 4; ++mt) {
#pragma unroll
    for (int r = 0; r < 4; ++r) {
      const int m  = m0 + wm + mt * 16 + quad * 4 + r;
      const int bb = m >> 9;
      const int l  = m & 511;
#pragma unroll
      for (int nt = 0; nt < 4; ++nt) {
        const int n = n0 + wn + nt * 16 + fr;
        const int h = n / DH_;
        const int d = n - h * DH_;
        dst[(((size_t)bb * H_ + h) * L_ + l) * DH_ + d] = f2bf(acc[mt][nt][r]);
      }
    }
  }
}

// ---------------------------------------------------------------------------
// Kernel 3: MFMA attention v5 — max-free softmax, spill-free, single S pass.
//   p_unnorm = exp(s) (masked -> 0); L = row sum via shfl + LDS;
//   normalization folded into V: V'[q] = V[q]/L_q;  O += P_unnorm^T V'.
//   vlen==0 degenerate: e = (k<=q) -> exactly np's uniform-row result.
//   LDS rows padded to 36 (72B stride) -> fragment reads conflict-free.
// ---------------------------------------------------------------------------
__global__ __launch_bounds__(256, 2) void attn_mfma(
    const uint16_t* __restrict__ qh, const uint16_t* __restrict__ kh,
    const uint16_t* __restrict__ vh, const int* __restrict__ lens,
    float* __restrict__ out) {
  const int bh = blockIdx.x;
  const int b  = bh >> 4;
  const int h  = bh & 15;
  const int t    = threadIdx.x;
  const int w    = t >> 6;
  const int lane = t & 63;
  const int l15  = lane & 15;
  const int quad = lane >> 4;

  const int qlen = lens[b];
  const int vlen = lens[32 + b];
  const bool deg = (vlen == 0);
  const size_t head = (size_t)bh * HEADELEMS;

  __shared__ uint16_t Pt[4][128][36];  // 36864 B  [wave][k_loc][q_loc] (unnorm e)
  __shared__ uint16_t Vt[48][36];      //  3456 B  [d][q_loc] raw -> scaled
  __shared__ float    prt[4][32];      //   512 B  per-wave row sums

  const uint16_t* qbase = qh + head;
  const uint16_t* kbase = kh + head;
  const uint16_t* vbase = vh + head;

  f32x4 Oacc[8][3];
#pragma unroll
  for (int i = 0; i < 8; ++i)
#pragma unroll
    for (int dt = 0; dt < 3; ++dt) Oacc[i][dt] = f32x4{0.f, 0.f, 0.f, 0.f};

  for (int g = 0; g < 16; ++g) {
    const int q0 = g * 32;
    const int lim = q0 + 31 - 16 * w;   // tile i active iff 64*i <= lim

    __syncthreads();   // B0: prev-iter PV done reading Pt/Vt

    // ---- stage Vt[d][q_loc] raw bf16: 192 threads x 16B ----
    if (t < 192) {
      const int vq = t & 31, oct = t >> 5;      // oct = 0..5, 8 d's each
      uint4 u = *(const uint4*)(vbase + (size_t)(q0 + vq) * DH_ + oct * 8);
      const int d0 = oct * 8;
      Vt[d0 + 0][vq] = (uint16_t)(u.x);
      Vt[d0 + 1][vq] = (uint16_t)(u.x >> 16);
      Vt[d0 + 2][vq] = (uint16_t)(u.y);
      Vt[d0 + 3][vq] = (uint16_t)(u.y >> 16);
      Vt[d0 + 4][vq] = (uint16_t)(u.z);
      Vt[d0 + 5][vq] = (uint16_t)(u.z >> 16);
      Vt[d0 + 6][vq] = (uint16_t)(u.w);
      Vt[d0 + 7][vq] = (uint16_t)(u.w >> 16);
    }

    // ---- Q A-fragments (2 m-tiles x 2 K-steps), d 48..63 zero-padded ----
    bf16x8 aq[2][2];
#pragma unroll
    for (int mt = 0; mt < 2; ++mt) {
      const uint16_t* qp = qbase + (size_t)(q0 + mt * 16 + l15) * DH_;
      aq[mt][0] = *(const bf16x8*)(qp + quad * 8);
      bf16x8 zz = {0, 0, 0, 0, 0, 0, 0, 0};
      aq[mt][1] = zz;
      if (quad < 2) aq[mt][1] = *(const bf16x8*)(qp + 32 + quad * 8);
    }

    // ---- single pass: S-MFMA -> e=exp(s) -> row-sum + pack to Pt ----
    float lrun[2][4];
#pragma unroll
    for (int mt = 0; mt < 2; ++mt)
#pragma unroll
      for (int r = 0; r < 4; ++r) lrun[mt][r] = 0.0f;

#pragma unroll
    for (int i = 0; i < 8; ++i) {
      if (64 * i > lim) continue;   // wave-uniform causal tile skip
      const int kb = 64 * i + 16 * w;
      f32x4 s0 = {0.f, 0.f, 0.f, 0.f};
      f32x4 s1 = {0.f, 0.f, 0.f, 0.f};
      if (!deg) {
        const uint16_t* kp = kbase + (size_t)(kb + l15) * DH_;
        bf16x8 bk0 = *(const bf16x8*)(kp + quad * 8);
        bf16x8 bk1 = {0, 0, 0, 0, 0, 0, 0, 0};
        if (quad < 2) bk1 = *(const bf16x8*)(kp + 32 + quad * 8);
        s0 = __builtin_amdgcn_mfma_f32_16x16x32_bf16(aq[0][0], bk0, s0, 0, 0, 0);
        s0 = __builtin_amdgcn_mfma_f32_16x16x32_bf16(aq[0][1], bk1, s0, 0, 0, 0);
        s1 = __builtin_amdgcn_mfma_f32_16x16x32_bf16(aq[1][0], bk0, s1, 0, 0, 0);
        s1 = __builtin_amdgcn_mfma_f32_16x16x32_bf16(aq[1][1], bk1, s1, 0, 0, 0);
      }
      const int kc  = kb + l15;
      const int row = i * 16 + l15;
#pragma unroll
      for (int mt = 0; mt < 2; ++mt) {
        f32x4 sv = (mt == 0) ? s0 : s1;
        float p4[4];
#pragma unroll
        for (int r = 0; r < 4; ++r) {
          const int qrow = q0 + mt * 16 + quad * 4 + r;
          float e;
          if (deg) {
            e = (kc <= qrow) ? 1.0f : 0.0f;
          } else {
            // scale already folded into qh via WQ
            e = (kc < vlen && kc <= qrow) ? __expf(sv[r]) : 0.0f;
          }
          lrun[mt][r] += e;
          p4[r] = e;
        }
        const int col = mt * 16 + quad * 4;
        *(uint32_t*)&Pt[w][row][col]     = pack2bf(p4[0], p4[1]);
        *(uint32_t*)&Pt[w][row][col + 2] = pack2bf(p4[2], p4[3]);
      }
    }

    // ---- 16-lane sum reduce; write per-wave partials ----
#pragma unroll
    for (int mt = 0; mt < 2; ++mt)
#pragma unroll
      for (int r = 0; r < 4; ++r) {
        float l = lrun[mt][r];
#pragma unroll
        for (int off = 1; off < 16; off <<= 1) l += __shfl_xor(l, off, 64);
        lrun[mt][r] = l;
      }
    if (l15 == 0) {
#pragma unroll
      for (int mt = 0; mt < 2; ++mt)
#pragma unroll
        for (int r = 0; r < 4; ++r)
          prt[w][mt * 16 + quad * 4 + r] = lrun[mt][r];
    }
    __syncthreads();   // B1: prt + Pt + Vt-raw visible

    // ---- scale Vt rows by 1/L_q in place (q = t&31 is j-invariant) ----
    {
      const int q = t & 31;
      const float inv = __builtin_amdgcn_rcpf(
          prt[0][q] + prt[1][q] + prt[2][q] + prt[3][q]);
#pragma unroll
      for (int j = 0; j < 6; ++j) {
        const int d = (t >> 5) + 8 * j;
        float f = __uint_as_float((uint32_t)Vt[d][q] << 16) * inv;
        Vt[d][q] = f2bf(f);
      }
    }
    __syncthreads();   // B2: scaled Vt visible

    // ---- PV MFMAs: Oacc[k_loc][d] += P^T[k][q] V'[q][d] ----
    bf16x8 bv[3];
#pragma unroll
    for (int dt = 0; dt < 3; ++dt)
      bv[dt] = lds_frag8(&Vt[dt * 16 + l15][quad * 8]);
#pragma unroll
    for (int i = 0; i < 8; ++i) {
      if (64 * i > lim) continue;
      bf16x8 ap = lds_frag8(&Pt[w][i * 16 + l15][quad * 8]);
#pragma unroll
      for (int dt = 0; dt < 3; ++dt)
        Oacc[i][dt] = __builtin_amdgcn_mfma_f32_16x16x32_bf16(
            ap, bv[dt], Oacc[i][dt], 0, 0, 0);
    }
  }

  // ---- epilogue: Q_len row mask, fp32 out [B][L][H*DH] ----
#pragma unroll
  for (int i = 0; i < 8; ++i) {
#pragma unroll
    for (int r = 0; r < 4; ++r) {
      const int k_abs = 64 * i + 16 * w + quad * 4 + r;
      const float msk = (k_abs < qlen) ? 1.0f : 0.0f;
      float* orow = out + (size_t)(b * L_ + k_abs) * DOUT_ + h * DH_;
#pragma unroll
      for (int dt = 0; dt < 3; ++dt)
        orow[dt * 16 + l15] = Oacc[i][dt][r] * msk;
    }
  }
}

// ---------------------------------------------------------------------------
// launch
// ---------------------------------------------------------------------------
extern "C" void kernel_launch(void* const* d_in, const int* in_sizes, int n_in,
                              void* d_out, int out_size, void* d_ws, size_t ws_size,
                              hipStream_t stream) {
  const float* Qs  = (const float*)d_in[0];
  const float* Kse = (const float*)d_in[1];
  const float* Vs  = (const float*)d_in[2];
  const float* WQ  = (const float*)d_in[3];
  const float* WK  = (const float*)d_in[4];
  const float* WV  = (const float*)d_in[5];
  const int*   Qlen = (const int*)d_in[6];
  const int*   Vlen = (const int*)d_in[7];
  float* out = (float*)d_out;

  char* ws = (char*)d_ws;
  int* lens = (int*)ws;
  uint16_t* qh  = (uint16_t*)(ws + 256);
  uint16_t* kh  = qh + (size_t)B_ * H_ * L_ * DH_;
  uint16_t* vh  = kh + (size_t)B_ * H_ * L_ * DH_;
  uint16_t* Wt  = vh + (size_t)B_ * H_ * L_ * DH_;

  lens_kernel<<<1, 64, 0, stream>>>(Qlen, Vlen, lens);
  wconv_kernel<<<dim3(3, 192, 3), 256, 0, stream>>>(WQ, WK, WV, Wt);
  mfma_proj<<<dim3(MROWS / 128, DOUT_ / 256, 3), 512, 0, stream>>>(
      Qs, Kse, Vs, Wt, qh, kh, vh);
  attn_mfma<<<NHEADS, 256, 0, stream>>>(qh, kh, vh, lens, out);
}